// Round 3
// baseline (2696.505 us; speedup 1.0000x reference)
//
#include <hip/hip_runtime.h>
#include <hip/hip_bf16.h>
#include <stdint.h>

#define N_NODES 40962
#define LATENT  512
#define N_EDGES 655392
#define NFREQ   32
#define NOISE_C 16

typedef unsigned short u16;
typedef unsigned char u8;
typedef __attribute__((ext_vector_type(8))) short short8;
typedef __attribute__((ext_vector_type(4))) float f32x4;
typedef __attribute__((ext_vector_type(2))) float f32x2;

__device__ __forceinline__ float bf2f(u16 u) {
  return __uint_as_float(((uint32_t)u) << 16);
}
__device__ __forceinline__ u16 f2bf(float f) {
  uint32_t u = __float_as_uint(f);
  u += 0x7fffu + ((u >> 16) & 1u);   // RNE
  return (u16)(u >> 16);
}

// ---- fp8 helpers (HW cvt when available; manual e4m3fn fallback, both self-consistent) ----
__device__ __forceinline__ u8 f2fp8(float f) {
#if __has_builtin(__builtin_amdgcn_cvt_pk_fp8_f32)
  int pk = __builtin_amdgcn_cvt_pk_fp8_f32(f, f, 0, false);
  return (u8)(pk & 0xff);
#else
  uint32_t x = __float_as_uint(f);
  uint32_t s = (x >> 24) & 0x80;
  uint32_t y = x & 0x7fffffff;
  if (__uint_as_float(y) >= 448.f) return (u8)(s | 0x7e);
  y += 0xfffff + ((y >> 20) & 1);
  int e = (int)(y >> 23) - 127 + 7;
  uint32_t m = (y >> 20) & 7;
  if (e < 1) return (u8)s;
  if (e > 15 || (e == 15 && m == 7)) return (u8)(s | 0x7e);
  return (u8)(s | ((uint32_t)e << 3) | m);
#endif
}

__device__ __forceinline__ void fp8x4_to_f32(uint32_t w, float* o) {
#if __has_builtin(__builtin_amdgcn_cvt_pk_f32_fp8)
  f32x2 lo = __builtin_amdgcn_cvt_pk_f32_fp8(w, false);
  f32x2 hi = __builtin_amdgcn_cvt_pk_f32_fp8(w, true);
  o[0] = lo.x; o[1] = lo.y; o[2] = hi.x; o[3] = hi.y;
#else
  #pragma unroll
  for (int i = 0; i < 4; ++i) {
    uint32_t u = (w >> (8 * i)) & 0xff;
    uint32_t e = (u >> 3) & 15, m = u & 7, s = (u & 0x80) << 24;
    o[i] = (e == 0) ? __uint_as_float(s)
                    : __uint_as_float(s | ((e + 120) << 23) | (m << 20));
  }
#endif
}

// bijective XCD-chunked remap (m204): contiguous wg chunk per XCD
__device__ __forceinline__ int xcd_remap(int id, int nwg) {
  int q = nwg >> 3, r = nwg & 7;
  int xc = id & 7, jj = id >> 3;
  return (xc < r ? xc * (q + 1) : r * (q + 1) + (xc - r) * q) + jj;
}

// ---------------- noise embedding -> cond (N,16) ----------------
__global__ void cond_kernel(const float* __restrict__ noise,
                            const float* __restrict__ w1, const float* __restrict__ b1,
                            const float* __restrict__ w2, const float* __restrict__ b2,
                            float* __restrict__ cond)
{
  int n = blockIdx.x * blockDim.x + threadIdx.x;
  if (n >= N_NODES) return;
  float nv = noise[n];
  float emb[2 * NFREQ];
  #pragma unroll
  for (int f = 0; f < NFREQ; ++f) {
    float ph = nv * (0.39269908169872414f * (float)(f + 1)); // 2pi/16 * (f+1)
    emb[f] = __sinf(ph);
    emb[NFREQ + f] = __cosf(ph);
  }
  float h[NOISE_C];
  #pragma unroll
  for (int c = 0; c < NOISE_C; ++c) {
    float a = b1[c];
    for (int j = 0; j < 2 * NFREQ; ++j) a = fmaf(emb[j], w1[j * NOISE_C + c], a);
    h[c] = a * (1.f / (1.f + __expf(-a)));  // silu
  }
  #pragma unroll
  for (int c2 = 0; c2 < NOISE_C; ++c2) {
    float a = b2[c2];
    #pragma unroll
    for (int c = 0; c < NOISE_C; ++c) a = fmaf(h[c], w2[c * NOISE_C + c2], a);
    cond[(size_t)n * NOISE_C + c2] = a;
  }
}

// ---- weight convert + transpose: out[(blk*6+m)][j][k] = W_m[blk][k][j] in bf16 ----
__global__ void conv_weights(const float* __restrict__ wq, const float* __restrict__ wk,
                             const float* __restrict__ wv, const float* __restrict__ wo,
                             const float* __restrict__ m1, const float* __restrict__ m2,
                             u16* __restrict__ out)
{
  __shared__ float tile[32][33];
  int z = blockIdx.z;
  int t6 = z >> 2;
  const float* W = (t6 == 0) ? wq : (t6 == 1) ? wk : (t6 == 2) ? wv :
                   (t6 == 3) ? wo : (t6 == 4) ? m1 : m2;
  W += (size_t)(z & 3) * 262144;
  u16* O = out + (size_t)((z & 3) * 6 + t6) * 262144;
  int tx = threadIdx.x, ty = threadIdx.y;
  int j0 = blockIdx.x * 32, k0 = blockIdx.y * 32;
  #pragma unroll
  for (int r = ty; r < 32; r += 8)
    tile[r][tx] = W[(size_t)(k0 + r) * 512 + j0 + tx];
  __syncthreads();
  #pragma unroll
  for (int r = ty; r < 32; r += 8)
    O[(size_t)(j0 + r) * 512 + k0 + tx] = f2bf(tile[tx][r]);
}

// pack qkv biases
__global__ void pack_bias(const float* __restrict__ bq, const float* __restrict__ bk,
                          const float* __restrict__ bv, float* __restrict__ bqkv)
{
  int idx = blockIdx.x * 256 + threadIdx.x;
  if (idx >= 4 * 1536) return;
  int i = idx / 1536, c = idx % 1536;
  float v = (c < 512) ? bq[i * 512 + c] : (c < 1024) ? bk[i * 512 + c - 512]
                                                     : bv[i * 512 + c - 1024];
  bqkv[idx] = v;
}

// ---------------- CSR build ----------------
__global__ void hist_kernel(const int* __restrict__ src, int* __restrict__ deg) {
  int e = blockIdx.x * 256 + threadIdx.x;
  if (e < N_EDGES) atomicAdd(&deg[src[e]], 1);
}

__global__ __launch_bounds__(1024) void scan_kernel(const int* __restrict__ deg,
                                                    int* __restrict__ row_start)
{
  __shared__ int sums[1024];
  int t = threadIdx.x;
  const int chunk = (N_NODES + 1023) / 1024;
  int lo = t * chunk, hi = lo + chunk;
  if (lo > N_NODES) lo = N_NODES;
  if (hi > N_NODES) hi = N_NODES;
  int s = 0;
  for (int i = lo; i < hi; ++i) s += deg[i];
  sums[t] = s;
  __syncthreads();
  for (int off = 1; off < 1024; off <<= 1) {
    int v = (t >= off) ? sums[t - off] : 0;
    __syncthreads();
    sums[t] += v;
    __syncthreads();
  }
  int base = (t > 0) ? sums[t - 1] : 0;
  for (int i = lo; i < hi; ++i) { row_start[i] = base; base += deg[i]; }
  if (t == 1023) row_start[N_NODES] = sums[1023];
}

__global__ void scatter_kernel(const int* __restrict__ src, const int* __restrict__ dst,
                               const int* __restrict__ row_start, int* __restrict__ cursor,
                               int* __restrict__ csr_dst)
{
  int e = blockIdx.x * 256 + threadIdx.x;
  if (e >= N_EDGES) return;
  int s = src[e];
  int p = atomicAdd(&cursor[s], 1);
  csr_dst[row_start[s] + p] = dst[e];
}

// ---------------- fused LayerNorm + FiLM -> bf16, 32 nodes/block ----------------
#define LN_NPB 32
__global__ __launch_bounds__(256, 4) void ln_film(
  const float* __restrict__ x, const float* __restrict__ cond,
  const float* __restrict__ sw, const float* __restrict__ sb,
  const float* __restrict__ bw, const float* __restrict__ bb,
  u16* __restrict__ yb)
{
  int t = threadIdx.x;
  int nbase = blockIdx.x * LN_NPB;
  int nlocal = N_NODES - nbase; if (nlocal > LN_NPB) nlocal = LN_NPB;

  // per-thread FiLM weights (d0 = t, d1 = t+256), loaded once per block
  float swr[16][2], bwr[16][2];
  #pragma unroll
  for (int c = 0; c < 16; ++c) {
    swr[c][0] = sw[c * 512 + t];       swr[c][1] = sw[c * 512 + t + 256];
    bwr[c][0] = bw[c * 512 + t];       bwr[c][1] = bw[c * 512 + t + 256];
  }
  float sb0 = sb[t], sb1 = sb[t + 256];
  float bb0 = bb[t], bb1 = bb[t + 256];

  __shared__ float cl[LN_NPB][16];
  #pragma unroll
  for (int r = 0; r < (LN_NPB * 16) / 256; ++r) {
    int idx = r * 256 + t;
    int nn = nbase + (idx >> 4);
    cl[idx >> 4][idx & 15] = (nn < N_NODES) ? cond[(size_t)nn * 16 + (idx & 15)] : 0.f;
  }

  __shared__ float red[2][8];
  int wv_ = t >> 6, ln_ = t & 63;

  float v0 = x[(size_t)nbase * 512 + t];
  float v1 = x[(size_t)nbase * 512 + t + 256];
  for (int i = 0; i < nlocal; ++i) {
    float n0 = 0.f, n1 = 0.f;
    if (i + 1 < nlocal) {
      const float* xr = x + (size_t)(nbase + i + 1) * 512;
      n0 = xr[t]; n1 = xr[t + 256];
    }
    float s = v0 + v1, ss = v0 * v0 + v1 * v1;
    #pragma unroll
    for (int o = 32; o > 0; o >>= 1) { s += __shfl_down(s, o); ss += __shfl_down(ss, o); }
    if (ln_ == 0) { red[i & 1][wv_] = s; red[i & 1][4 + wv_] = ss; }
    __syncthreads();
    s  = red[i & 1][0] + red[i & 1][1] + red[i & 1][2] + red[i & 1][3];
    ss = red[i & 1][4] + red[i & 1][5] + red[i & 1][6] + red[i & 1][7];
    float mu = s * (1.f / 512.f);
    float rstd = rsqrtf(ss * (1.f / 512.f) - mu * mu + 1e-5f);
    float cc[16];
    #pragma unroll
    for (int c = 0; c < 16; ++c) cc[c] = cl[i][c];
    float sc0 = sb0, bi0 = bb0, sc1 = sb1, bi1 = bb1;
    #pragma unroll
    for (int c = 0; c < 16; ++c) {
      sc0 = fmaf(cc[c], swr[c][0], sc0);
      bi0 = fmaf(cc[c], bwr[c][0], bi0);
      sc1 = fmaf(cc[c], swr[c][1], sc1);
      bi1 = fmaf(cc[c], bwr[c][1], bi1);
    }
    size_t rowo = (size_t)(nbase + i) * 512;
    yb[rowo + t]       = f2bf((v0 - mu) * rstd * (1.f + sc0) + bi0);
    yb[rowo + t + 256] = f2bf((v1 - mu) * rstd * (1.f + sc1) + bi1);
    v0 = n0; v1 = n1;
  }
}

// ---- 256x256 8-wave counted-vmcnt bf16 MFMA GEMM for the qkv projection ----
// v3: relaxed barrier schedule -- with 128KB LDS only ONE block/CU is resident,
// so per-phase barriers lockstep all 8 waves and expose every latency hole
// (measured 10.9k cyc/K-tile vs the ~2.9k LDS-pipe floor). Now: 2 barriers +
// 1 counted vmcnt per K-tile, 2 MFMA clusters of 32, B-frags loaded once
// (24 ds_read_b128/K-tile = the minimum). Buffer-race safety:
//  - end-of-tile barrier => all waves done reading buf d before any wave's
//    top-of-next-tile stage targets buf d (issued-in-flight loads included).
//  - vmcnt(4)+barrier at tile top => all 8 loads of the incoming tile (from
//    all waves) have landed before any wave reads it. In-flight depth <= 8,
//    vmcnt never drained to 0 in the main loop.
__global__ __launch_bounds__(512, 2) void gemm256_qkv(
  const u16* __restrict__ A, const u16* __restrict__ Bt,
  const float* __restrict__ bias, u8* __restrict__ Cq)
{
  constexpr int M = N_NODES;
  constexpr int NBX = 6;                 // 1536 / 256
  constexpr int NT = 8;                  // 512 / 64
  __shared__ u16 As[2][256 * 64];
  __shared__ u16 Bs[2][256 * 64];
  int tid = threadIdx.x;
  int wid = tid >> 6, lane = tid & 63;
  int wm = wid >> 2, wn = wid & 3;       // 2 x 4 wave grid, per-wave C = 128x64
  int fm = lane & 15, fq = lane >> 4;
  int l3 = lane >> 3, l7 = lane & 7;
  int swz16 = (l7 ^ l3) * 8;             // inverse-swizzled source col (u16)

  int wg = xcd_remap(blockIdx.x, gridDim.x);
  int tn = (wg % NBX) * 256;
  int tm = (wg / NBX) * 256;

  f32x4 acc[8][4] = {};
  short8 af[4][2];    // A frags of current qm half
  short8 bfr[4][2];   // B frags of the wave's full 64-col slice

  auto stage_half = [&](u16* ldsmat, const u16* __restrict__ G, int rowbase,
                        int h, int t, bool clampM) {
    #pragma unroll
    for (int rr = 0; rr < 2; ++rr) {
      int rowblk = h * 128 + (wid * 2 + rr) * 8;       // uniform per wave
      int grow = rowbase + rowblk + l3;
      if (clampM && grow > M - 1) grow = M - 1;
      const u16* src = G + (size_t)grow * 512 + t * 64 + swz16;
      u16* dstb = ldsmat + rowblk * 64;
      __builtin_amdgcn_global_load_lds(
        (const __attribute__((address_space(1))) void*)(uintptr_t)src,
        (__attribute__((address_space(3))) void*)(uintptr_t)dstb, 16, 0, 0);
    }
  };

  auto load_a = [&](int d, int qm) {
    const u16* Ab = &As[d][0];
    #pragma unroll
    for (int i = 0; i < 4; ++i) {
      int ar = wm * 128 + qm * 64 + i * 16 + fm;
      #pragma unroll
      for (int ks = 0; ks < 2; ++ks)
        af[i][ks] = *(const short8*)(Ab + ar * 64 + ((ks * 32 + fq * 8) ^ ((fm & 7) * 8)));
    }
  };
  auto load_b_all = [&](int d) {
    const u16* Bb = &Bs[d][0];
    #pragma unroll
    for (int j = 0; j < 4; ++j) {
      int bc = wn * 64 + j * 16 + fm;
      #pragma unroll
      for (int ks = 0; ks < 2; ++ks)
        bfr[j][ks] = *(const short8*)(Bb + bc * 64 + ((ks * 32 + fq * 8) ^ ((fm & 7) * 8)));
    }
  };
  auto mma_half = [&](int qm) {
    __builtin_amdgcn_s_setprio(1);
    #pragma unroll
    for (int i = 0; i < 4; ++i)
      #pragma unroll
      for (int j = 0; j < 4; ++j)
        #pragma unroll
        for (int ks = 0; ks < 2; ++ks)
          acc[qm * 4 + i][j] = __builtin_amdgcn_mfma_f32_16x16x32_bf16(
              af[i][ks], bfr[j][ks], acc[qm * 4 + i][j], 0, 0, 0);
    __builtin_amdgcn_s_setprio(0);
  };

  // prologue: tile 0 -> buf 0 (8 loads/wave)
  stage_half(As[0], A, tm, 0, 0, true);
  stage_half(As[0], A, tm, 1, 0, true);
  stage_half(Bs[0], Bt, tn, 0, 0, false);
  stage_half(Bs[0], Bt, tn, 1, 0, false);

  #pragma unroll 2
  for (int t = 0; t < NT; ++t) {
    int d = t & 1;
    if (t + 1 < NT) {
      // issue low halves of tile t+1 (buffer d^1 safe: end-of-tile barrier of
      // t-1 guaranteed all readers of d^1 finished), THEN counted wait for
      // tile t's 8 loads, leaving the 4 new ones in flight.
      stage_half(As[d ^ 1], A, tm, 0, t + 1, true);
      stage_half(Bs[d ^ 1], Bt, tn, 0, t + 1, false);
      asm volatile("s_waitcnt vmcnt(4)" ::: "memory");
    } else {
      asm volatile("s_waitcnt vmcnt(0)" ::: "memory");
    }
    __builtin_amdgcn_sched_barrier(0);
    __builtin_amdgcn_s_barrier();          // all waves' tile-t loads landed
    __builtin_amdgcn_sched_barrier(0);
    load_a(d, 0);
    load_b_all(d);
    mma_half(0);                           // 32 MFMA
    if (t + 1 < NT) {
      stage_half(As[d ^ 1], A, tm, 1, t + 1, true);
      stage_half(Bs[d ^ 1], Bt, tn, 1, t + 1, false);
    }
    load_a(d, 1);
    mma_half(1);                           // 32 MFMA
    __builtin_amdgcn_sched_barrier(0);
    __builtin_amdgcn_s_barrier();          // all waves done reading buf d
    __builtin_amdgcn_sched_barrier(0);
  }

  // epilogue: q cols (<512) bf16, k/v cols fp8
  #pragma unroll
  for (int i = 0; i < 8; ++i) {
    int rowb = tm + wm * 128 + i * 16 + fq * 4;
    #pragma unroll
    for (int j = 0; j < 4; ++j) {
      int col = tn + wn * 64 + j * 16 + fm;
      float bvv = bias[col];
      #pragma unroll
      for (int r = 0; r < 4; ++r) {
        int gr = rowb + r;
        if (gr < M) {
          float v = acc[i][j][r] + bvv;
          u8* row_p = Cq + (size_t)gr * 2048;
          if (col < 512) *(u16*)(row_p + 2 * col) = f2bf(v);
          else           row_p[512 + col] = f2fp8(v);
        }
      }
    }
  }
}

// ---- 128x128 bf16 MFMA GEMM, double-buffered LDS (N=512 gemms) ----
// 16B-granule XOR swizzle (g ^= row&3) on BOTH sides: inverse-swizzled global
// source for global_load_lds (dest stays linear, rule #21) + swizzled ds_read.
// Row parity supplies the 5th bank bit -> reads land on the 8-slot/bank
// minimum (conflict-free).  MODE 0: fp32 out (+res). MODE 1: bf16 out (+relu).
template<int MODE, bool RELU, bool RES>
__global__ __launch_bounds__(256) void gemm_bt(
  const u16* __restrict__ A, const u16* __restrict__ Bt,
  const float* __restrict__ bias, const float* __restrict__ res,
  float* __restrict__ Cf, u16* __restrict__ Cb, int nbx)
{
  constexpr int M = N_NODES, K = 512;
  __shared__ u16 As[2 * 128 * 32];
  __shared__ u16 Bs[2 * 128 * 32];
  int tid = threadIdx.x;
  int wave = tid >> 6, lane = tid & 63;
  int wg = xcd_remap(blockIdx.x, gridDim.x);   // XCD-chunked: col-blocks of a panel share an XCD's L2
  int tn = (wg % nbx) * 128, tm = (wg / nbx) * 128;
  f32x4 acc[4][4] = {};
  int wm = (wave & 1) * 64, wn = (wave >> 1) * 64;
  int fm = lane & 15, fq = lane >> 4;
  int gsw = (fq ^ (fm & 3)) * 8;               // swizzled read granule (u16 offset)

  auto stage = [&](int buf, int k0) {
    #pragma unroll
    for (int rr = 0; rr < 2; ++rr) {
      int c = rr * 256 + tid;
      int row = c >> 2;
      int cb = (((c & 3) ^ (row & 3)) << 3);   // inverse-swizzled source granule
      int gr = tm + row; if (gr > M - 1) gr = M - 1;
      __builtin_amdgcn_global_load_lds(
        (const __attribute__((address_space(1))) void*)(uintptr_t)(A + (size_t)gr * K + (k0 + cb)),
        (__attribute__((address_space(3))) void*)(uintptr_t)(As + buf * 4096 + (size_t)(rr * 256 + wave * 64) * 8),
        16, 0, 0);
      int brow = tn + row;
      __builtin_amdgcn_global_load_lds(
        (const __attribute__((address_space(1))) void*)(uintptr_t)(Bt + (size_t)brow * K + (k0 + cb)),
        (__attribute__((address_space(3))) void*)(uintptr_t)(Bs + buf * 4096 + (size_t)(rr * 256 + wave * 64) * 8),
        16, 0, 0);
    }
  };

  stage(0, 0);
  #pragma unroll 4
  for (int it = 0; it < K / 32; ++it) {
    int cur = it & 1;
    __syncthreads();                 // drains cur-buf loads (vmcnt(0)+lgkm)
    if (it + 1 < K / 32) stage(cur ^ 1, (it + 1) * 32);  // fly during this MFMA stage
    const u16* Ab = As + cur * 4096;
    const u16* Bb = Bs + cur * 4096;
    short8 af[4], bf_[4];
    #pragma unroll
    for (int i = 0; i < 4; ++i) {
      af[i]  = *(const short8*)(Ab + (wm + i * 16 + fm) * 32 + gsw);
      bf_[i] = *(const short8*)(Bb + (wn + i * 16 + fm) * 32 + gsw);
    }
    #pragma unroll
    for (int mi = 0; mi < 4; ++mi)
      #pragma unroll
      for (int ni = 0; ni < 4; ++ni)
        acc[mi][ni] = __builtin_amdgcn_mfma_f32_16x16x32_bf16(af[mi], bf_[ni], acc[mi][ni], 0, 0, 0);
  }

  #pragma unroll
  for (int mi = 0; mi < 4; ++mi) {
    #pragma unroll
    for (int ni = 0; ni < 4; ++ni) {
      int col = tn + wn + ni * 16 + fm;
      float bvv = bias[col];
      int rowb = tm + wm + mi * 16 + fq * 4;
      #pragma unroll
      for (int r = 0; r < 4; ++r) {
        int gr = rowb + r;
        if (gr < M) {
          float v = acc[mi][ni][r] + bvv;
          if (RELU) v = fmaxf(v, 0.f);
          if (RES)  v += res[(size_t)gr * 512 + col];
          if (MODE == 0) Cf[(size_t)gr * 512 + col] = v;
          else           Cb[(size_t)gr * 512 + col] = f2bf(v);
        }
      }
    }
  }
}

// ---- gather-side online-softmax sparse attention; qkv row = [q bf16 1K | k fp8 512 | v fp8 512] ----
__global__ __launch_bounds__(256) void attn_kernel(
  const u8* __restrict__ qkv,
  const int* __restrict__ row_start, const int* __restrict__ csr_dst,
  u16* __restrict__ ab)
{
  int wave = threadIdx.x >> 6, lane = threadIdx.x & 63;
  int n = blockIdx.x * 4 + wave;
  if (n >= N_NODES) return;
  float qf[8];
  {
    short8 q8 = *(const short8*)(qkv + (size_t)n * 2048 + lane * 16);
    #pragma unroll
    for (int j = 0; j < 8; ++j) qf[j] = bf2f((u16)q8[j]);
  }
  float m = -1e30f, l = 0.f;
  float acc[8];
  #pragma unroll
  for (int j = 0; j < 8; ++j) acc[j] = 0.f;
  int e0 = row_start[n], e1 = row_start[n + 1];
  int deg = e1 - e0;
  if (deg > 0) {
    int koff = 1024 + lane * 8, voff = 1536 + lane * 8;
    int d0 = csr_dst[e0];
    int d1 = (deg > 1) ? csr_dst[e0 + 1] : d0;
    uint2 ku0 = *(const uint2*)(qkv + (size_t)d0 * 2048 + koff);
    uint2 vu0 = *(const uint2*)(qkv + (size_t)d0 * 2048 + voff);
    uint2 ku1 = *(const uint2*)(qkv + (size_t)d1 * 2048 + koff);
    uint2 vu1 = *(const uint2*)(qkv + (size_t)d1 * 2048 + voff);
    for (int t = 0; t < deg; t += 2) {
      int p0 = e0 + t + 2, p1 = e0 + t + 3;
      int dn0 = (p0 < e1) ? csr_dst[p0] : d0;
      int dn1 = (p1 < e1) ? csr_dst[p1] : d0;
      uint2 kn0 = *(const uint2*)(qkv + (size_t)dn0 * 2048 + koff);
      uint2 vn0 = *(const uint2*)(qkv + (size_t)dn0 * 2048 + voff);
      uint2 kn1 = *(const uint2*)(qkv + (size_t)dn1 * 2048 + koff);
      uint2 vn1 = *(const uint2*)(qkv + (size_t)dn1 * 2048 + voff);
      float k0f[8], k1f[8];
      fp8x4_to_f32(ku0.x, k0f); fp8x4_to_f32(ku0.y, k0f + 4);
      fp8x4_to_f32(ku1.x, k1f); fp8x4_to_f32(ku1.y, k1f + 4);
      float s0 = 0.f, s1 = 0.f;
      #pragma unroll
      for (int j = 0; j < 8; ++j) { s0 = fmaf(qf[j], k0f[j], s0); s1 = fmaf(qf[j], k1f[j], s1); }
      s0 += __shfl_xor(s0, 1); s1 += __shfl_xor(s1, 1);
      s0 += __shfl_xor(s0, 2); s1 += __shfl_xor(s1, 2);
      s0 += __shfl_xor(s0, 4); s1 += __shfl_xor(s1, 4);
      s0 += __shfl_xor(s0, 8); s1 += __shfl_xor(s1, 8);
      s0 *= 0.088388347648318447f;
      s1 = (t + 1 < deg) ? s1 * 0.088388347648318447f : -1e30f;
      float mx = fmaxf(m, fmaxf(s0, s1));
      float al = __expf(m - mx);
      float pp0 = __expf(s0 - mx);
      float pp1 = __expf(s1 - mx);
      l = l * al + pp0 + pp1;
      float v0f[8], v1f[8];
      fp8x4_to_f32(vu0.x, v0f); fp8x4_to_f32(vu0.y, v0f + 4);
      fp8x4_to_f32(vu1.x, v1f); fp8x4_to_f32(vu1.y, v1f + 4);
      #pragma unroll
      for (int j = 0; j < 8; ++j)
        acc[j] = fmaf(acc[j], al, fmaf(pp0, v0f[j], pp1 * v1f[j]));
      m = mx;
      ku0 = kn0; vu0 = vn0; ku1 = kn1; vu1 = vn1;
    }
  }
  float rl = (l > 0.f) ? 1.f / l : 0.f;
  short8 o8;
  #pragma unroll
  for (int j = 0; j < 8; ++j) o8[j] = (short)f2bf(acc[j] * rl);
  *(short8*)(ab + (size_t)n * 512 + lane * 8) = o8;
}

// ---------------- host ----------------
extern "C" void kernel_launch(void* const* d_in, const int* in_sizes, int n_in,
                              void* d_out, int out_size, void* d_ws, size_t ws_size,
                              hipStream_t stream)
{
  const float* x0    = (const float*)d_in[0];
  const int*   edge  = (const int*)d_in[1];
  const float* noise = (const float*)d_in[2];
  const float* f_w1  = (const float*)d_in[3];
  const float* f_b1  = (const float*)d_in[4];
  const float* f_w2  = (const float*)d_in[5];
  const float* f_b2  = (const float*)d_in[6];
  const float* s1_w  = (const float*)d_in[7];
  const float* s1_b  = (const float*)d_in[8];
  const float* b1_w  = (const float*)d_in[9];
  const float* b1_b  = (const float*)d_in[10];
  const float* wq    = (const float*)d_in[11];
  const float* bq    = (const float*)d_in[12];
  const float* wk    = (const float*)d_in[13];
  const float* bk    = (const float*)d_in[14];
  const float* wv    = (const float*)d_in[15];
  const float* bv    = (const float*)d_in[16];
  const float* wo    = (const float*)d_in[17];
  const float* bo    = (const float*)d_in[18];
  const float* s2_w  = (const float*)d_in[19];
  const float* s2_b  = (const float*)d_in[20];
  const float* b2_w  = (const float*)d_in[21];
  const float* b2_b  = (const float*)d_in[22];
  const float* m_w1  = (const float*)d_in[23];
  const float* m_b1  = (const float*)d_in[24];
  const float* m_w2  = (const float*)d_in[25];
  const float* m_b2  = (const float*)d_in[26];
  float* xout = (float*)d_out;

  char* w = (char*)d_ws;
  auto alloc = [&](size_t bytes) -> char* {
    char* p = w; w += (bytes + 255) & ~(size_t)255; return p;
  };
  u16*  Wt     = (u16*)alloc(24ull * 512 * 512 * 2);
  float* cond  = (float*)alloc((size_t)N_NODES * 16 * 4);
  float* bqkv  = (float*)alloc(4 * 1536 * 4);
  u16*  ybf    = (u16*)alloc((size_t)N_NODES * 512 * 2);
  u16*  hbf    = (u16*)alloc((size_t)N_NODES * 512 * 2);
  u8*   qkvb   = (u8*)alloc((size_t)N_NODES * 2048);
  int*  deg    = (int*)alloc((size_t)N_NODES * 4);
  int*  cursor = (int*)alloc((size_t)N_NODES * 4);
  int*  rowst  = (int*)alloc((size_t)(N_NODES + 1) * 4);
  int*  csrd   = (int*)alloc((size_t)N_EDGES * 4);

  conv_weights<<<dim3(16, 16, 24), dim3(32, 8), 0, stream>>>(wq, wk, wv, wo, m_w1, m_w2, Wt);
  cond_kernel<<<(N_NODES + 255) / 256, 256, 0, stream>>>(noise, f_w1, f_b1, f_w2, f_b2, cond);
  pack_bias<<<(4 * 1536 + 255) / 256, 256, 0, stream>>>(bq, bk, bv, bqkv);
  hipMemsetAsync(deg, 0, (size_t)N_NODES * 4, stream);
  hipMemsetAsync(cursor, 0, (size_t)N_NODES * 4, stream);
  const int* src = edge;
  const int* dst = edge + N_EDGES;
  hist_kernel<<<(N_EDGES + 255) / 256, 256, 0, stream>>>(src, deg);
  scan_kernel<<<1, 1024, 0, stream>>>(deg, rowst);
  scatter_kernel<<<(N_EDGES + 255) / 256, 256, 0, stream>>>(src, dst, rowst, cursor, csrd);

  const int g_ln  = (N_NODES + LN_NPB - 1) / LN_NPB;   // 1281 strip blocks
  const int g_qkv = 6 * ((N_NODES + 255) / 256);       // 966 blocks, 256x256 tiles
  const int g_512 = 4 * ((N_NODES + 127) / 128);       // 1284 blocks, 128x128 tiles
  const float* xin = x0;
  for (int i = 0; i < 4; ++i) {
    const u16* Wb = Wt + (size_t)i * 6 * 262144;
    ln_film<<<g_ln, 256, 0, stream>>>(xin, cond, s1_w + i * 8192, s1_b + i * 512,
                                      b1_w + i * 8192, b1_b + i * 512, ybf);
    gemm256_qkv<<<g_qkv, 512, 0, stream>>>(ybf, Wb, bqkv + i * 1536, qkvb);
    attn_kernel<<<(N_NODES + 3) / 4, 256, 0, stream>>>(qkvb, rowst, csrd, ybf);
    gemm_bt<0, false, true><<<g_512, 256, 0, stream>>>(ybf, Wb + 3 * 262144,
                                                       bo + i * 512, xin, xout, nullptr, 4);
    ln_film<<<g_ln, 256, 0, stream>>>(xout, cond, s2_w + i * 8192, s2_b + i * 512,
                                      b2_w + i * 8192, b2_b + i * 512, ybf);
    gemm_bt<1, true, false><<<g_512, 256, 0, stream>>>(ybf, Wb + 4 * 262144,
                                                       m_b1 + i * 512, nullptr, nullptr, hbf, 4);
    gemm_bt<0, false, true><<<g_512, 256, 0, stream>>>(hbf, Wb + 5 * 262144,
                                                       m_b2 + i * 512, xout, xout, nullptr, 4);
    xin = xout;
  }
}

// Round 5
// 2642.326 us; speedup vs baseline: 1.0205x; 1.0205x over previous
//
#include <hip/hip_runtime.h>
#include <hip/hip_bf16.h>
#include <stdint.h>

#define N_NODES 40962
#define LATENT  512
#define N_EDGES 655392
#define NFREQ   32
#define NOISE_C 16

typedef unsigned short u16;
typedef unsigned char u8;
typedef __attribute__((ext_vector_type(8))) short short8;
typedef __attribute__((ext_vector_type(4))) float f32x4;
typedef __attribute__((ext_vector_type(2))) float f32x2;

__device__ __forceinline__ float bf2f(u16 u) {
  return __uint_as_float(((uint32_t)u) << 16);
}
__device__ __forceinline__ u16 f2bf(float f) {
  uint32_t u = __float_as_uint(f);
  u += 0x7fffu + ((u >> 16) & 1u);   // RNE
  return (u16)(u >> 16);
}

// ---- fp8 helpers (HW cvt when available; manual e4m3fn fallback, both self-consistent) ----
__device__ __forceinline__ u8 f2fp8(float f) {
#if __has_builtin(__builtin_amdgcn_cvt_pk_fp8_f32)
  int pk = __builtin_amdgcn_cvt_pk_fp8_f32(f, f, 0, false);
  return (u8)(pk & 0xff);
#else
  uint32_t x = __float_as_uint(f);
  uint32_t s = (x >> 24) & 0x80;
  uint32_t y = x & 0x7fffffff;
  if (__uint_as_float(y) >= 448.f) return (u8)(s | 0x7e);
  y += 0xfffff + ((y >> 20) & 1);
  int e = (int)(y >> 23) - 127 + 7;
  uint32_t m = (y >> 20) & 7;
  if (e < 1) return (u8)s;
  if (e > 15 || (e == 15 && m == 7)) return (u8)(s | 0x7e);
  return (u8)(s | ((uint32_t)e << 3) | m);
#endif
}

__device__ __forceinline__ void fp8x4_to_f32(uint32_t w, float* o) {
#if __has_builtin(__builtin_amdgcn_cvt_pk_f32_fp8)
  f32x2 lo = __builtin_amdgcn_cvt_pk_f32_fp8(w, false);
  f32x2 hi = __builtin_amdgcn_cvt_pk_f32_fp8(w, true);
  o[0] = lo.x; o[1] = lo.y; o[2] = hi.x; o[3] = hi.y;
#else
  #pragma unroll
  for (int i = 0; i < 4; ++i) {
    uint32_t u = (w >> (8 * i)) & 0xff;
    uint32_t e = (u >> 3) & 15, m = u & 7, s = (u & 0x80) << 24;
    o[i] = (e == 0) ? __uint_as_float(s)
                    : __uint_as_float(s | ((e + 120) << 23) | (m << 20));
  }
#endif
}

// bijective XCD-chunked remap (m204): contiguous wg chunk per XCD
__device__ __forceinline__ int xcd_remap(int id, int nwg) {
  int q = nwg >> 3, r = nwg & 7;
  int xc = id & 7, jj = id >> 3;
  return (xc < r ? xc * (q + 1) : r * (q + 1) + (xc - r) * q) + jj;
}

// ---------------- noise embedding -> cond (N,16) ----------------
__global__ void cond_kernel(const float* __restrict__ noise,
                            const float* __restrict__ w1, const float* __restrict__ b1,
                            const float* __restrict__ w2, const float* __restrict__ b2,
                            float* __restrict__ cond)
{
  int n = blockIdx.x * blockDim.x + threadIdx.x;
  if (n >= N_NODES) return;
  float nv = noise[n];
  float emb[2 * NFREQ];
  #pragma unroll
  for (int f = 0; f < NFREQ; ++f) {
    float ph = nv * (0.39269908169872414f * (float)(f + 1)); // 2pi/16 * (f+1)
    emb[f] = __sinf(ph);
    emb[NFREQ + f] = __cosf(ph);
  }
  float h[NOISE_C];
  #pragma unroll
  for (int c = 0; c < NOISE_C; ++c) {
    float a = b1[c];
    for (int j = 0; j < 2 * NFREQ; ++j) a = fmaf(emb[j], w1[j * NOISE_C + c], a);
    h[c] = a * (1.f / (1.f + __expf(-a)));  // silu
  }
  #pragma unroll
  for (int c2 = 0; c2 < NOISE_C; ++c2) {
    float a = b2[c2];
    #pragma unroll
    for (int c = 0; c < NOISE_C; ++c) a = fmaf(h[c], w2[c * NOISE_C + c2], a);
    cond[(size_t)n * NOISE_C + c2] = a;
  }
}

// ---- weight convert + transpose: out[(blk*6+m)][j][k] = W_m[blk][k][j] in bf16 ----
__global__ void conv_weights(const float* __restrict__ wq, const float* __restrict__ wk,
                             const float* __restrict__ wv, const float* __restrict__ wo,
                             const float* __restrict__ m1, const float* __restrict__ m2,
                             u16* __restrict__ out)
{
  __shared__ float tile[32][33];
  int z = blockIdx.z;
  int t6 = z >> 2;
  const float* W = (t6 == 0) ? wq : (t6 == 1) ? wk : (t6 == 2) ? wv :
                   (t6 == 3) ? wo : (t6 == 4) ? m1 : m2;
  W += (size_t)(z & 3) * 262144;
  u16* O = out + (size_t)((z & 3) * 6 + t6) * 262144;
  int tx = threadIdx.x, ty = threadIdx.y;
  int j0 = blockIdx.x * 32, k0 = blockIdx.y * 32;
  #pragma unroll
  for (int r = ty; r < 32; r += 8)
    tile[r][tx] = W[(size_t)(k0 + r) * 512 + j0 + tx];
  __syncthreads();
  #pragma unroll
  for (int r = ty; r < 32; r += 8)
    O[(size_t)(j0 + r) * 512 + k0 + tx] = f2bf(tile[tx][r]);
}

// pack qkv biases
__global__ void pack_bias(const float* __restrict__ bq, const float* __restrict__ bk,
                          const float* __restrict__ bv, float* __restrict__ bqkv)
{
  int idx = blockIdx.x * 256 + threadIdx.x;
  if (idx >= 4 * 1536) return;
  int i = idx / 1536, c = idx % 1536;
  float v = (c < 512) ? bq[i * 512 + c] : (c < 1024) ? bk[i * 512 + c - 512]
                                                     : bv[i * 512 + c - 1024];
  bqkv[idx] = v;
}

// ---------------- CSR build ----------------
__global__ void hist_kernel(const int* __restrict__ src, int* __restrict__ deg) {
  int e = blockIdx.x * 256 + threadIdx.x;
  if (e < N_EDGES) atomicAdd(&deg[src[e]], 1);
}

__global__ __launch_bounds__(1024) void scan_kernel(const int* __restrict__ deg,
                                                    int* __restrict__ row_start)
{
  __shared__ int sums[1024];
  int t = threadIdx.x;
  const int chunk = (N_NODES + 1023) / 1024;
  int lo = t * chunk, hi = lo + chunk;
  if (lo > N_NODES) lo = N_NODES;
  if (hi > N_NODES) hi = N_NODES;
  int s = 0;
  for (int i = lo; i < hi; ++i) s += deg[i];
  sums[t] = s;
  __syncthreads();
  for (int off = 1; off < 1024; off <<= 1) {
    int v = (t >= off) ? sums[t - off] : 0;
    __syncthreads();
    sums[t] += v;
    __syncthreads();
  }
  int base = (t > 0) ? sums[t - 1] : 0;
  for (int i = lo; i < hi; ++i) { row_start[i] = base; base += deg[i]; }
  if (t == 1023) row_start[N_NODES] = sums[1023];
}

__global__ void scatter_kernel(const int* __restrict__ src, const int* __restrict__ dst,
                               const int* __restrict__ row_start, int* __restrict__ cursor,
                               int* __restrict__ csr_dst)
{
  int e = blockIdx.x * 256 + threadIdx.x;
  if (e >= N_EDGES) return;
  int s = src[e];
  int p = atomicAdd(&cursor[s], 1);
  csr_dst[row_start[s] + p] = dst[e];
}

// ---------------- fused LayerNorm + FiLM -> bf16, 32 nodes/block ----------------
// v3: thread t owns the ADJACENT d-pair {2t, 2t+1}: float2 weight/x loads
// (8 B/lane, G13), packed 2xbf16 dword store. NO min-waves launch bound --
// the v2 (256,4) bound capped the allocator at 128 VGPRs with ~64 weight
// regs live, forcing scratch spills re-read every node-iter (the ~97 us).
#define LN_NPB 32
__global__ __launch_bounds__(256) void ln_film(
  const float* __restrict__ x, const float* __restrict__ cond,
  const float* __restrict__ sw, const float* __restrict__ sb,
  const float* __restrict__ bw, const float* __restrict__ bb,
  u16* __restrict__ yb)
{
  int t = threadIdx.x;
  int nbase = blockIdx.x * LN_NPB;
  int nlocal = N_NODES - nbase; if (nlocal > LN_NPB) nlocal = LN_NPB;

  // per-thread FiLM weights for d = 2t, 2t+1 (float2, loaded once per block)
  f32x2 swr[16], bwr[16];
  #pragma unroll
  for (int c = 0; c < 16; ++c) {
    swr[c] = *(const f32x2*)(sw + c * 512 + 2 * t);
    bwr[c] = *(const f32x2*)(bw + c * 512 + 2 * t);
  }
  f32x2 sbv = *(const f32x2*)(sb + 2 * t);
  f32x2 bbv = *(const f32x2*)(bb + 2 * t);

  __shared__ float cl[LN_NPB][16];
  #pragma unroll
  for (int r = 0; r < (LN_NPB * 16) / 256; ++r) {
    int idx = r * 256 + t;
    int nn = nbase + (idx >> 4);
    cl[idx >> 4][idx & 15] = (nn < N_NODES) ? cond[(size_t)nn * 16 + (idx & 15)] : 0.f;
  }

  __shared__ float red[2][8];
  int wv_ = t >> 6, ln_ = t & 63;

  f32x2 v = *(const f32x2*)(x + (size_t)nbase * 512 + 2 * t);
  for (int i = 0; i < nlocal; ++i) {
    // branchless clamped prefetch of next node's pair
    int nrow = nbase + i + 1; if (nrow > N_NODES - 1) nrow = N_NODES - 1;
    f32x2 nv2 = *(const f32x2*)(x + (size_t)nrow * 512 + 2 * t);
    float s = v.x + v.y, ss = v.x * v.x + v.y * v.y;
    #pragma unroll
    for (int o = 32; o > 0; o >>= 1) { s += __shfl_down(s, o); ss += __shfl_down(ss, o); }
    if (ln_ == 0) { red[i & 1][wv_] = s; red[i & 1][4 + wv_] = ss; }
    __syncthreads();
    s  = red[i & 1][0] + red[i & 1][1] + red[i & 1][2] + red[i & 1][3];
    ss = red[i & 1][4] + red[i & 1][5] + red[i & 1][6] + red[i & 1][7];
    float mu = s * (1.f / 512.f);
    float rstd = rsqrtf(ss * (1.f / 512.f) - mu * mu + 1e-5f);
    float sc0 = sbv.x, sc1 = sbv.y, bi0 = bbv.x, bi1 = bbv.y;
    #pragma unroll
    for (int c = 0; c < 16; ++c) {
      float cc = cl[i][c];
      sc0 = fmaf(cc, swr[c].x, sc0);
      sc1 = fmaf(cc, swr[c].y, sc1);
      bi0 = fmaf(cc, bwr[c].x, bi0);
      bi1 = fmaf(cc, bwr[c].y, bi1);
    }
    float o0 = (v.x - mu) * rstd * (1.f + sc0) + bi0;
    float o1 = (v.y - mu) * rstd * (1.f + sc1) + bi1;
    uint32_t pk = (uint32_t)f2bf(o0) | ((uint32_t)f2bf(o1) << 16);
    *(uint32_t*)(yb + (size_t)(nbase + i) * 512 + 2 * t) = pk;
    v = nv2;
  }
}

// ---- 256x256 8-wave counted-vmcnt bf16 MFMA GEMM for the qkv projection ----
// (frozen from R2: 2 barriers + counted vmcnt per K-tile, B-frags loaded once)
__global__ __launch_bounds__(512, 2) void gemm256_qkv(
  const u16* __restrict__ A, const u16* __restrict__ Bt,
  const float* __restrict__ bias, u8* __restrict__ Cq)
{
  constexpr int M = N_NODES;
  constexpr int NBX = 6;                 // 1536 / 256
  constexpr int NT = 8;                  // 512 / 64
  __shared__ u16 As[2][256 * 64];
  __shared__ u16 Bs[2][256 * 64];
  int tid = threadIdx.x;
  int wid = tid >> 6, lane = tid & 63;
  int wm = wid >> 2, wn = wid & 3;       // 2 x 4 wave grid, per-wave C = 128x64
  int fm = lane & 15, fq = lane >> 4;
  int l3 = lane >> 3, l7 = lane & 7;
  int swz16 = (l7 ^ l3) * 8;             // inverse-swizzled source col (u16)

  int wg = xcd_remap(blockIdx.x, gridDim.x);
  int tn = (wg % NBX) * 256;
  int tm = (wg / NBX) * 256;

  f32x4 acc[8][4] = {};
  short8 af[4][2];    // A frags of current qm half
  short8 bfr[4][2];   // B frags of the wave's full 64-col slice

  auto stage_half = [&](u16* ldsmat, const u16* __restrict__ G, int rowbase,
                        int h, int t, bool clampM) {
    #pragma unroll
    for (int rr = 0; rr < 2; ++rr) {
      int rowblk = h * 128 + (wid * 2 + rr) * 8;       // uniform per wave
      int grow = rowbase + rowblk + l3;
      if (clampM && grow > M - 1) grow = M - 1;
      const u16* src = G + (size_t)grow * 512 + t * 64 + swz16;
      u16* dstb = ldsmat + rowblk * 64;
      __builtin_amdgcn_global_load_lds(
        (const __attribute__((address_space(1))) void*)(uintptr_t)src,
        (__attribute__((address_space(3))) void*)(uintptr_t)dstb, 16, 0, 0);
    }
  };

  auto load_a = [&](int d, int qm) {
    const u16* Ab = &As[d][0];
    #pragma unroll
    for (int i = 0; i < 4; ++i) {
      int ar = wm * 128 + qm * 64 + i * 16 + fm;
      #pragma unroll
      for (int ks = 0; ks < 2; ++ks)
        af[i][ks] = *(const short8*)(Ab + ar * 64 + ((ks * 32 + fq * 8) ^ ((fm & 7) * 8)));
    }
  };
  auto load_b_all = [&](int d) {
    const u16* Bb = &Bs[d][0];
    #pragma unroll
    for (int j = 0; j < 4; ++j) {
      int bc = wn * 64 + j * 16 + fm;
      #pragma unroll
      for (int ks = 0; ks < 2; ++ks)
        bfr[j][ks] = *(const short8*)(Bb + bc * 64 + ((ks * 32 + fq * 8) ^ ((fm & 7) * 8)));
    }
  };
  auto mma_half = [&](int qm) {
    __builtin_amdgcn_s_setprio(1);
    #pragma unroll
    for (int i = 0; i < 4; ++i)
      #pragma unroll
      for (int j = 0; j < 4; ++j)
        #pragma unroll
        for (int ks = 0; ks < 2; ++ks)
          acc[qm * 4 + i][j] = __builtin_amdgcn_mfma_f32_16x16x32_bf16(
              af[i][ks], bfr[j][ks], acc[qm * 4 + i][j], 0, 0, 0);
    __builtin_amdgcn_s_setprio(0);
  };

  // prologue: tile 0 -> buf 0 (8 loads/wave)
  stage_half(As[0], A, tm, 0, 0, true);
  stage_half(As[0], A, tm, 1, 0, true);
  stage_half(Bs[0], Bt, tn, 0, 0, false);
  stage_half(Bs[0], Bt, tn, 1, 0, false);

  #pragma unroll 2
  for (int t = 0; t < NT; ++t) {
    int d = t & 1;
    if (t + 1 < NT) {
      stage_half(As[d ^ 1], A, tm, 0, t + 1, true);
      stage_half(Bs[d ^ 1], Bt, tn, 0, t + 1, false);
      asm volatile("s_waitcnt vmcnt(4)" ::: "memory");
    } else {
      asm volatile("s_waitcnt vmcnt(0)" ::: "memory");
    }
    __builtin_amdgcn_sched_barrier(0);
    __builtin_amdgcn_s_barrier();          // all waves' tile-t loads landed
    __builtin_amdgcn_sched_barrier(0);
    load_a(d, 0);
    load_b_all(d);
    mma_half(0);                           // 32 MFMA
    if (t + 1 < NT) {
      stage_half(As[d ^ 1], A, tm, 1, t + 1, true);
      stage_half(Bs[d ^ 1], Bt, tn, 1, t + 1, false);
    }
    load_a(d, 1);
    mma_half(1);                           // 32 MFMA
    __builtin_amdgcn_sched_barrier(0);
    __builtin_amdgcn_s_barrier();          // all waves done reading buf d
    __builtin_amdgcn_sched_barrier(0);
  }

  // epilogue: q cols (<512) bf16, k/v cols fp8
  #pragma unroll
  for (int i = 0; i < 8; ++i) {
    int rowb = tm + wm * 128 + i * 16 + fq * 4;
    #pragma unroll
    for (int j = 0; j < 4; ++j) {
      int col = tn + wn * 64 + j * 16 + fm;
      float bvv = bias[col];
      #pragma unroll
      for (int r = 0; r < 4; ++r) {
        int gr = rowb + r;
        if (gr < M) {
          float v = acc[i][j][r] + bvv;
          u8* row_p = Cq + (size_t)gr * 2048;
          if (col < 512) *(u16*)(row_p + 2 * col) = f2bf(v);
          else           row_p[512 + col] = f2fp8(v);
        }
      }
    }
  }
}

// ---- 128x128 bf16 MFMA GEMM, double-buffered LDS (N=512 gemms) ----
// 16B-granule XOR swizzle (g ^= row&3) on BOTH sides: inverse-swizzled global
// source for global_load_lds (dest stays linear, rule #21) + swizzled ds_read.
template<int MODE, bool RELU, bool RES>
__global__ __launch_bounds__(256) void gemm_bt(
  const u16* __restrict__ A, const u16* __restrict__ Bt,
  const float* __restrict__ bias, const float* __restrict__ res,
  float* __restrict__ Cf, u16* __restrict__ Cb, int nbx)
{
  constexpr int M = N_NODES, K = 512;
  __shared__ u16 As[2 * 128 * 32];
  __shared__ u16 Bs[2 * 128 * 32];
  int tid = threadIdx.x;
  int wave = tid >> 6, lane = tid & 63;
  int wg = xcd_remap(blockIdx.x, gridDim.x);   // XCD-chunked: col-blocks of a panel share an XCD's L2
  int tn = (wg % nbx) * 128, tm = (wg / nbx) * 128;
  f32x4 acc[4][4] = {};
  int wm = (wave & 1) * 64, wn = (wave >> 1) * 64;
  int fm = lane & 15, fq = lane >> 4;
  int gsw = (fq ^ (fm & 3)) * 8;               // swizzled read granule (u16 offset)

  auto stage = [&](int buf, int k0) {
    #pragma unroll
    for (int rr = 0; rr < 2; ++rr) {
      int c = rr * 256 + tid;
      int row = c >> 2;
      int cb = (((c & 3) ^ (row & 3)) << 3);   // inverse-swizzled source granule
      int gr = tm + row; if (gr > M - 1) gr = M - 1;
      __builtin_amdgcn_global_load_lds(
        (const __attribute__((address_space(1))) void*)(uintptr_t)(A + (size_t)gr * K + (k0 + cb)),
        (__attribute__((address_space(3))) void*)(uintptr_t)(As + buf * 4096 + (size_t)(rr * 256 + wave * 64) * 8),
        16, 0, 0);
      int brow = tn + row;
      __builtin_amdgcn_global_load_lds(
        (const __attribute__((address_space(1))) void*)(uintptr_t)(Bt + (size_t)brow * K + (k0 + cb)),
        (__attribute__((address_space(3))) void*)(uintptr_t)(Bs + buf * 4096 + (size_t)(rr * 256 + wave * 64) * 8),
        16, 0, 0);
    }
  };

  stage(0, 0);
  #pragma unroll 4
  for (int it = 0; it < K / 32; ++it) {
    int cur = it & 1;
    __syncthreads();                 // drains cur-buf loads (vmcnt(0)+lgkm)
    if (it + 1 < K / 32) stage(cur ^ 1, (it + 1) * 32);  // fly during this MFMA stage
    const u16* Ab = As + cur * 4096;
    const u16* Bb = Bs + cur * 4096;
    short8 af[4], bf_[4];
    #pragma unroll
    for (int i = 0; i < 4; ++i) {
      af[i]  = *(const short8*)(Ab + (wm + i * 16 + fm) * 32 + gsw);
      bf_[i] = *(const short8*)(Bb + (wn + i * 16 + fm) * 32 + gsw);
    }
    #pragma unroll
    for (int mi = 0; mi < 4; ++mi)
      #pragma unroll
      for (int ni = 0; ni < 4; ++ni)
        acc[mi][ni] = __builtin_amdgcn_mfma_f32_16x16x32_bf16(af[mi], bf_[ni], acc[mi][ni], 0, 0, 0);
  }

  #pragma unroll
  for (int mi = 0; mi < 4; ++mi) {
    #pragma unroll
    for (int ni = 0; ni < 4; ++ni) {
      int col = tn + wn + ni * 16 + fm;
      float bvv = bias[col];
      int rowb = tm + wm + mi * 16 + fq * 4;
      #pragma unroll
      for (int r = 0; r < 4; ++r) {
        int gr = rowb + r;
        if (gr < M) {
          float v = acc[mi][ni][r] + bvv;
          if (RELU) v = fmaxf(v, 0.f);
          if (RES)  v += res[(size_t)gr * 512 + col];
          if (MODE == 0) Cf[(size_t)gr * 512 + col] = v;
          else           Cb[(size_t)gr * 512 + col] = f2bf(v);
        }
      }
    }
  }
}

// ---- gather-side online-softmax sparse attention; qkv row = [q bf16 1K | k fp8 512 | v fp8 512] ----
__global__ __launch_bounds__(256) void attn_kernel(
  const u8* __restrict__ qkv,
  const int* __restrict__ row_start, const int* __restrict__ csr_dst,
  u16* __restrict__ ab)
{
  int wave = threadIdx.x >> 6, lane = threadIdx.x & 63;
  int n = blockIdx.x * 4 + wave;
  if (n >= N_NODES) return;
  float qf[8];
  {
    short8 q8 = *(const short8*)(qkv + (size_t)n * 2048 + lane * 16);
    #pragma unroll
    for (int j = 0; j < 8; ++j) qf[j] = bf2f((u16)q8[j]);
  }
  float m = -1e30f, l = 0.f;
  float acc[8];
  #pragma unroll
  for (int j = 0; j < 8; ++j) acc[j] = 0.f;
  int e0 = row_start[n], e1 = row_start[n + 1];
  int deg = e1 - e0;
  if (deg > 0) {
    int koff = 1024 + lane * 8, voff = 1536 + lane * 8;
    int d0 = csr_dst[e0];
    int d1 = (deg > 1) ? csr_dst[e0 + 1] : d0;
    uint2 ku0 = *(const uint2*)(qkv + (size_t)d0 * 2048 + koff);
    uint2 vu0 = *(const uint2*)(qkv + (size_t)d0 * 2048 + voff);
    uint2 ku1 = *(const uint2*)(qkv + (size_t)d1 * 2048 + koff);
    uint2 vu1 = *(const uint2*)(qkv + (size_t)d1 * 2048 + voff);
    for (int t = 0; t < deg; t += 2) {
      int p0 = e0 + t + 2, p1 = e0 + t + 3;
      int dn0 = (p0 < e1) ? csr_dst[p0] : d0;
      int dn1 = (p1 < e1) ? csr_dst[p1] : d0;
      uint2 kn0 = *(const uint2*)(qkv + (size_t)dn0 * 2048 + koff);
      uint2 vn0 = *(const uint2*)(qkv + (size_t)dn0 * 2048 + voff);
      uint2 kn1 = *(const uint2*)(qkv + (size_t)dn1 * 2048 + koff);
      uint2 vn1 = *(const uint2*)(qkv + (size_t)dn1 * 2048 + voff);
      float k0f[8], k1f[8];
      fp8x4_to_f32(ku0.x, k0f); fp8x4_to_f32(ku0.y, k0f + 4);
      fp8x4_to_f32(ku1.x, k1f); fp8x4_to_f32(ku1.y, k1f + 4);
      float s0 = 0.f, s1 = 0.f;
      #pragma unroll
      for (int j = 0; j < 8; ++j) { s0 = fmaf(qf[j], k0f[j], s0); s1 = fmaf(qf[j], k1f[j], s1); }
      s0 += __shfl_xor(s0, 1); s1 += __shfl_xor(s1, 1);
      s0 += __shfl_xor(s0, 2); s1 += __shfl_xor(s1, 2);
      s0 += __shfl_xor(s0, 4); s1 += __shfl_xor(s1, 4);
      s0 += __shfl_xor(s0, 8); s1 += __shfl_xor(s1, 8);
      s0 *= 0.088388347648318447f;
      s1 = (t + 1 < deg) ? s1 * 0.088388347648318447f : -1e30f;
      float mx = fmaxf(m, fmaxf(s0, s1));
      float al = __expf(m - mx);
      float pp0 = __expf(s0 - mx);
      float pp1 = __expf(s1 - mx);
      l = l * al + pp0 + pp1;
      float v0f[8], v1f[8];
      fp8x4_to_f32(vu0.x, v0f); fp8x4_to_f32(vu0.y, v0f + 4);
      fp8x4_to_f32(vu1.x, v1f); fp8x4_to_f32(vu1.y, v1f + 4);
      #pragma unroll
      for (int j = 0; j < 8; ++j)
        acc[j] = fmaf(acc[j], al, fmaf(pp0, v0f[j], pp1 * v1f[j]));
      m = mx;
      ku0 = kn0; vu0 = vn0; ku1 = kn1; vu1 = vn1;
    }
  }
  float rl = (l > 0.f) ? 1.f / l : 0.f;
  short8 o8;
  #pragma unroll
  for (int j = 0; j < 8; ++j) o8[j] = (short)f2bf(acc[j] * rl);
  *(short8*)(ab + (size_t)n * 512 + lane * 8) = o8;
}

// ---------------- host ----------------
extern "C" void kernel_launch(void* const* d_in, const int* in_sizes, int n_in,
                              void* d_out, int out_size, void* d_ws, size_t ws_size,
                              hipStream_t stream)
{
  const float* x0    = (const float*)d_in[0];
  const int*   edge  = (const int*)d_in[1];
  const float* noise = (const float*)d_in[2];
  const float* f_w1  = (const float*)d_in[3];
  const float* f_b1  = (const float*)d_in[4];
  const float* f_w2  = (const float*)d_in[5];
  const float* f_b2  = (const float*)d_in[6];
  const float* s1_w  = (const float*)d_in[7];
  const float* s1_b  = (const float*)d_in[8];
  const float* b1_w  = (const float*)d_in[9];
  const float* b1_b  = (const float*)d_in[10];
  const float* wq    = (const float*)d_in[11];
  const float* bq    = (const float*)d_in[12];
  const float* wk    = (const float*)d_in[13];
  const float* bk    = (const float*)d_in[14];
  const float* wv    = (const float*)d_in[15];
  const float* bv    = (const float*)d_in[16];
  const float* wo    = (const float*)d_in[17];
  const float* bo    = (const float*)d_in[18];
  const float* s2_w  = (const float*)d_in[19];
  const float* s2_b  = (const float*)d_in[20];
  const float* b2_w  = (const float*)d_in[21];
  const float* b2_b  = (const float*)d_in[22];
  const float* m_w1  = (const float*)d_in[23];
  const float* m_b1  = (const float*)d_in[24];
  const float* m_w2  = (const float*)d_in[25];
  const float* m_b2  = (const float*)d_in[26];
  float* xout = (float*)d_out;

  char* w = (char*)d_ws;
  auto alloc = [&](size_t bytes) -> char* {
    char* p = w; w += (bytes + 255) & ~(size_t)255; return p;
  };
  u16*  Wt     = (u16*)alloc(24ull * 512 * 512 * 2);
  float* cond  = (float*)alloc((size_t)N_NODES * 16 * 4);
  float* bqkv  = (float*)alloc(4 * 1536 * 4);
  u16*  ybf    = (u16*)alloc((size_t)N_NODES * 512 * 2);
  u16*  hbf    = (u16*)alloc((size_t)N_NODES * 512 * 2);
  u8*   qkvb   = (u8*)alloc((size_t)N_NODES * 2048);
  int*  deg    = (int*)alloc((size_t)N_NODES * 4);
  int*  cursor = (int*)alloc((size_t)N_NODES * 4);
  int*  rowst  = (int*)alloc((size_t)(N_NODES + 1) * 4);
  int*  csrd   = (int*)alloc((size_t)N_EDGES * 4);

  conv_weights<<<dim3(16, 16, 24), dim3(32, 8), 0, stream>>>(wq, wk, wv, wo, m_w1, m_w2, Wt);
  cond_kernel<<<(N_NODES + 255) / 256, 256, 0, stream>>>(noise, f_w1, f_b1, f_w2, f_b2, cond);
  pack_bias<<<(4 * 1536 + 255) / 256, 256, 0, stream>>>(bq, bk, bv, bqkv);
  hipMemsetAsync(deg, 0, (size_t)N_NODES * 4, stream);
  hipMemsetAsync(cursor, 0, (size_t)N_NODES * 4, stream);
  const int* src = edge;
  const int* dst = edge + N_EDGES;
  hist_kernel<<<(N_EDGES + 255) / 256, 256, 0, stream>>>(src, deg);
  scan_kernel<<<1, 1024, 0, stream>>>(deg, rowst);
  scatter_kernel<<<(N_EDGES + 255) / 256, 256, 0, stream>>>(src, dst, rowst, cursor, csrd);

  const int g_ln  = (N_NODES + LN_NPB - 1) / LN_NPB;   // 1281 strip blocks
  const int g_qkv = 6 * ((N_NODES + 255) / 256);       // 966 blocks, 256x256 tiles
  const int g_512 = 4 * ((N_NODES + 127) / 128);       // 1284 blocks, 128x128 tiles
  const float* xin = x0;
  for (int i = 0; i < 4; ++i) {
    const u16* Wb = Wt + (size_t)i * 6 * 262144;
    ln_film<<<g_ln, 256, 0, stream>>>(xin, cond, s1_w + i * 8192, s1_b + i * 512,
                                      b1_w + i * 8192, b1_b + i * 512, ybf);
    gemm256_qkv<<<g_qkv, 512, 0, stream>>>(ybf, Wb, bqkv + i * 1536, qkvb);
    attn_kernel<<<(N_NODES + 3) / 4, 256, 0, stream>>>(qkvb, rowst, csrd, ybf);
    gemm_bt<0, false, true><<<g_512, 256, 0, stream>>>(ybf, Wb + 3 * 262144,
                                                       bo + i * 512, xin, xout, nullptr, 4);
    ln_film<<<g_ln, 256, 0, stream>>>(xout, cond, s2_w + i * 8192, s2_b + i * 512,
                                      b2_w + i * 8192, b2_b + i * 512, ybf);
    gemm_bt<1, true, false><<<g_512, 256, 0, stream>>>(ybf, Wb + 4 * 262144,
                                                       m_b1 + i * 512, nullptr, nullptr, hbf, 4);
    gemm_bt<0, false, true><<<g_512, 256, 0, stream>>>(hbf, Wb + 5 * 262144,
                                                       m_b2 + i * 512, xout, xout, nullptr, 4);
    xin = xout;
  }
}

// Round 6
// 2600.917 us; speedup vs baseline: 1.0368x; 1.0159x over previous
//
#include <hip/hip_runtime.h>
#include <hip/hip_bf16.h>
#include <stdint.h>

#define N_NODES 40962
#define LATENT  512
#define N_EDGES 655392
#define NFREQ   32
#define NOISE_C 16

typedef unsigned short u16;
typedef unsigned char u8;
typedef __attribute__((ext_vector_type(8))) short short8;
typedef __attribute__((ext_vector_type(4))) float f32x4;
typedef __attribute__((ext_vector_type(2))) float f32x2;

__device__ __forceinline__ float bf2f(u16 u) {
  return __uint_as_float(((uint32_t)u) << 16);
}
__device__ __forceinline__ u16 f2bf(float f) {
  uint32_t u = __float_as_uint(f);
  u += 0x7fffu + ((u >> 16) & 1u);   // RNE
  return (u16)(u >> 16);
}

// ---- fp8 helpers (HW cvt when available; manual e4m3fn fallback, both self-consistent) ----
__device__ __forceinline__ u8 f2fp8(float f) {
#if __has_builtin(__builtin_amdgcn_cvt_pk_fp8_f32)
  int pk = __builtin_amdgcn_cvt_pk_fp8_f32(f, f, 0, false);
  return (u8)(pk & 0xff);
#else
  uint32_t x = __float_as_uint(f);
  uint32_t s = (x >> 24) & 0x80;
  uint32_t y = x & 0x7fffffff;
  if (__uint_as_float(y) >= 448.f) return (u8)(s | 0x7e);
  y += 0xfffff + ((y >> 20) & 1);
  int e = (int)(y >> 23) - 127 + 7;
  uint32_t m = (y >> 20) & 7;
  if (e < 1) return (u8)s;
  if (e > 15 || (e == 15 && m == 7)) return (u8)(s | 0x7e);
  return (u8)(s | ((uint32_t)e << 3) | m);
#endif
}

__device__ __forceinline__ void fp8x4_to_f32(uint32_t w, float* o) {
#if __has_builtin(__builtin_amdgcn_cvt_pk_f32_fp8)
  f32x2 lo = __builtin_amdgcn_cvt_pk_f32_fp8(w, false);
  f32x2 hi = __builtin_amdgcn_cvt_pk_f32_fp8(w, true);
  o[0] = lo.x; o[1] = lo.y; o[2] = hi.x; o[3] = hi.y;
#else
  #pragma unroll
  for (int i = 0; i < 4; ++i) {
    uint32_t u = (w >> (8 * i)) & 0xff;
    uint32_t e = (u >> 3) & 15, m = u & 7, s = (u & 0x80) << 24;
    o[i] = (e == 0) ? __uint_as_float(s)
                    : __uint_as_float(s | ((e + 120) << 23) | (m << 20));
  }
#endif
}

// bijective XCD-chunked remap (m204): contiguous wg chunk per XCD
__device__ __forceinline__ int xcd_remap(int id, int nwg) {
  int q = nwg >> 3, r = nwg & 7;
  int xc = id & 7, jj = id >> 3;
  return (xc < r ? xc * (q + 1) : r * (q + 1) + (xc - r) * q) + jj;
}

// ---------------- noise embedding -> cond (N,16) ----------------
__global__ void cond_kernel(const float* __restrict__ noise,
                            const float* __restrict__ w1, const float* __restrict__ b1,
                            const float* __restrict__ w2, const float* __restrict__ b2,
                            float* __restrict__ cond)
{
  int n = blockIdx.x * blockDim.x + threadIdx.x;
  if (n >= N_NODES) return;
  float nv = noise[n];
  float emb[2 * NFREQ];
  #pragma unroll
  for (int f = 0; f < NFREQ; ++f) {
    float ph = nv * (0.39269908169872414f * (float)(f + 1)); // 2pi/16 * (f+1)
    emb[f] = __sinf(ph);
    emb[NFREQ + f] = __cosf(ph);
  }
  float h[NOISE_C];
  #pragma unroll
  for (int c = 0; c < NOISE_C; ++c) {
    float a = b1[c];
    for (int j = 0; j < 2 * NFREQ; ++j) a = fmaf(emb[j], w1[j * NOISE_C + c], a);
    h[c] = a * (1.f / (1.f + __expf(-a)));  // silu
  }
  #pragma unroll
  for (int c2 = 0; c2 < NOISE_C; ++c2) {
    float a = b2[c2];
    #pragma unroll
    for (int c = 0; c < NOISE_C; ++c) a = fmaf(h[c], w2[c * NOISE_C + c2], a);
    cond[(size_t)n * NOISE_C + c2] = a;
  }
}

// ---- weight convert + transpose: out[(blk*6+m)][j][k] = W_m[blk][k][j] in bf16 ----
__global__ void conv_weights(const float* __restrict__ wq, const float* __restrict__ wk,
                             const float* __restrict__ wv, const float* __restrict__ wo,
                             const float* __restrict__ m1, const float* __restrict__ m2,
                             u16* __restrict__ out)
{
  __shared__ float tile[32][33];
  int z = blockIdx.z;
  int t6 = z >> 2;
  const float* W = (t6 == 0) ? wq : (t6 == 1) ? wk : (t6 == 2) ? wv :
                   (t6 == 3) ? wo : (t6 == 4) ? m1 : m2;
  W += (size_t)(z & 3) * 262144;
  u16* O = out + (size_t)((z & 3) * 6 + t6) * 262144;
  int tx = threadIdx.x, ty = threadIdx.y;
  int j0 = blockIdx.x * 32, k0 = blockIdx.y * 32;
  #pragma unroll
  for (int r = ty; r < 32; r += 8)
    tile[r][tx] = W[(size_t)(k0 + r) * 512 + j0 + tx];
  __syncthreads();
  #pragma unroll
  for (int r = ty; r < 32; r += 8)
    O[(size_t)(j0 + r) * 512 + k0 + tx] = f2bf(tile[tx][r]);
}

// pack qkv biases
__global__ void pack_bias(const float* __restrict__ bq, const float* __restrict__ bk,
                          const float* __restrict__ bv, float* __restrict__ bqkv)
{
  int idx = blockIdx.x * 256 + threadIdx.x;
  if (idx >= 4 * 1536) return;
  int i = idx / 1536, c = idx % 1536;
  float v = (c < 512) ? bq[i * 512 + c] : (c < 1024) ? bk[i * 512 + c - 512]
                                                     : bv[i * 512 + c - 1024];
  bqkv[idx] = v;
}

// ---------------- CSR build ----------------
__global__ void hist_kernel(const int* __restrict__ src, int* __restrict__ deg) {
  int e = blockIdx.x * 256 + threadIdx.x;
  if (e < N_EDGES) atomicAdd(&deg[src[e]], 1);
}

__global__ __launch_bounds__(1024) void scan_kernel(const int* __restrict__ deg,
                                                    int* __restrict__ row_start)
{
  __shared__ int sums[1024];
  int t = threadIdx.x;
  const int chunk = (N_NODES + 1023) / 1024;
  int lo = t * chunk, hi = lo + chunk;
  if (lo > N_NODES) lo = N_NODES;
  if (hi > N_NODES) hi = N_NODES;
  int s = 0;
  for (int i = lo; i < hi; ++i) s += deg[i];
  sums[t] = s;
  __syncthreads();
  for (int off = 1; off < 1024; off <<= 1) {
    int v = (t >= off) ? sums[t - off] : 0;
    __syncthreads();
    sums[t] += v;
    __syncthreads();
  }
  int base = (t > 0) ? sums[t - 1] : 0;
  for (int i = lo; i < hi; ++i) { row_start[i] = base; base += deg[i]; }
  if (t == 1023) row_start[N_NODES] = sums[1023];
}

__global__ void scatter_kernel(const int* __restrict__ src, const int* __restrict__ dst,
                               const int* __restrict__ row_start, int* __restrict__ cursor,
                               int* __restrict__ csr_dst)
{
  int e = blockIdx.x * 256 + threadIdx.x;
  if (e >= N_EDGES) return;
  int s = src[e];
  int p = atomicAdd(&cursor[s], 1);
  csr_dst[row_start[s] + p] = dst[e];
}

// ---------------- fused LayerNorm + FiLM -> bf16, 32 nodes/block ----------------
// v4: barrier-free. Each wave redundantly reads the FULL row (2KB, L1-shared
// across the block's 4 waves) and reduces with a 6-level shfl_xor butterfly;
// lane owns d = {w*128+2l, +1}. No per-iter __syncthreads / cross-wave LDS.
// Weight registers are PINNED with an empty asm (rule #17) -- the previous
// versions' ~90us came from the compiler sinking the "loop-invariant" weight
// loads into the node loop (VGPR_Count=32 signature): 2.7GB of L2 re-reads
// per dispatch. The pin makes the 64 weight values opaque so they must stay
// in registers.
#define LN_NPB 32
__global__ __launch_bounds__(256) void ln_film(
  const float* __restrict__ x, const float* __restrict__ cond,
  const float* __restrict__ sw, const float* __restrict__ sb,
  const float* __restrict__ bw, const float* __restrict__ bb,
  u16* __restrict__ yb)
{
  int t = threadIdx.x;
  int w = t >> 6, l = t & 63;
  int nbase = blockIdx.x * LN_NPB;
  int nlocal = N_NODES - nbase; if (nlocal > LN_NPB) nlocal = LN_NPB;
  int d0 = w * 128 + 2 * l;

  // per-lane FiLM weights for its d-pair, loaded once and pinned
  float sw0[16], sw1[16], bw0[16], bw1[16];
  #pragma unroll
  for (int c = 0; c < 16; ++c) {
    f32x2 a = *(const f32x2*)(sw + c * 512 + d0);
    f32x2 b = *(const f32x2*)(bw + c * 512 + d0);
    sw0[c] = a.x; sw1[c] = a.y; bw0[c] = b.x; bw1[c] = b.y;
  }
  #pragma unroll
  for (int c = 0; c < 16; ++c)
    asm volatile("" : "+v"(sw0[c]), "+v"(sw1[c]), "+v"(bw0[c]), "+v"(bw1[c]));
  f32x2 sbv = *(const f32x2*)(sb + d0);
  f32x2 bbv = *(const f32x2*)(bb + d0);

  // cond strip staged once (single barrier; loop itself is barrier-free)
  __shared__ float cl[LN_NPB][16];
  for (int idx = t; idx < LN_NPB * 16; idx += 256) {
    int nn = nbase + (idx >> 4);
    cl[idx >> 4][idx & 15] = (nn < N_NODES) ? cond[(size_t)nn * 16 + (idx & 15)] : 0.f;
  }
  __syncthreads();

  // prefetch node 0
  const float* xr0 = x + (size_t)nbase * 512;
  f32x4 r0 = *(const f32x4*)(xr0 + l * 8);
  f32x4 r1 = *(const f32x4*)(xr0 + l * 8 + 4);
  f32x2 xp = *(const f32x2*)(xr0 + d0);

  for (int i = 0; i < nlocal; ++i) {
    int nrow = nbase + i + 1; if (nrow > N_NODES - 1) nrow = N_NODES - 1;
    const float* xr = x + (size_t)nrow * 512;
    f32x4 n0 = *(const f32x4*)(xr + l * 8);
    f32x4 n1 = *(const f32x4*)(xr + l * 8 + 4);
    f32x2 np = *(const f32x2*)(xr + d0);

    float s  = (r0.x + r0.y) + (r0.z + r0.w) + (r1.x + r1.y) + (r1.z + r1.w);
    float ss = fmaf(r0.x, r0.x, fmaf(r0.y, r0.y, fmaf(r0.z, r0.z,
               fmaf(r0.w, r0.w, fmaf(r1.x, r1.x, fmaf(r1.y, r1.y,
               fmaf(r1.z, r1.z, r1.w * r1.w)))))));
    #pragma unroll
    for (int o = 1; o < 64; o <<= 1) { s += __shfl_xor(s, o); ss += __shfl_xor(ss, o); }
    float mu = s * (1.f / 512.f);
    float rstd = rsqrtf(ss * (1.f / 512.f) - mu * mu + 1e-5f);

    float sc0 = sbv.x, sc1 = sbv.y, bi0 = bbv.x, bi1 = bbv.y;
    #pragma unroll
    for (int c = 0; c < 16; ++c) {
      float cc = cl[i][c];
      sc0 = fmaf(cc, sw0[c], sc0);
      sc1 = fmaf(cc, sw1[c], sc1);
      bi0 = fmaf(cc, bw0[c], bi0);
      bi1 = fmaf(cc, bw1[c], bi1);
    }
    float o0 = (xp.x - mu) * rstd * (1.f + sc0) + bi0;
    float o1 = (xp.y - mu) * rstd * (1.f + sc1) + bi1;
    uint32_t pk = (uint32_t)f2bf(o0) | ((uint32_t)f2bf(o1) << 16);
    *(uint32_t*)(yb + (size_t)(nbase + i) * 512 + d0) = pk;
    r0 = n0; r1 = n1; xp = np;
  }
}

// ---- 256x256 8-wave counted-vmcnt bf16 MFMA GEMM for the qkv projection ----
// (frozen from R2: 2 barriers + counted vmcnt per K-tile, B-frags loaded once)
__global__ __launch_bounds__(512, 2) void gemm256_qkv(
  const u16* __restrict__ A, const u16* __restrict__ Bt,
  const float* __restrict__ bias, u8* __restrict__ Cq)
{
  constexpr int M = N_NODES;
  constexpr int NBX = 6;                 // 1536 / 256
  constexpr int NT = 8;                  // 512 / 64
  __shared__ u16 As[2][256 * 64];
  __shared__ u16 Bs[2][256 * 64];
  int tid = threadIdx.x;
  int wid = tid >> 6, lane = tid & 63;
  int wm = wid >> 2, wn = wid & 3;       // 2 x 4 wave grid, per-wave C = 128x64
  int fm = lane & 15, fq = lane >> 4;
  int l3 = lane >> 3, l7 = lane & 7;
  int swz16 = (l7 ^ l3) * 8;             // inverse-swizzled source col (u16)

  int wg = xcd_remap(blockIdx.x, gridDim.x);
  int tn = (wg % NBX) * 256;
  int tm = (wg / NBX) * 256;

  f32x4 acc[8][4] = {};
  short8 af[4][2];    // A frags of current qm half
  short8 bfr[4][2];   // B frags of the wave's full 64-col slice

  auto stage_half = [&](u16* ldsmat, const u16* __restrict__ G, int rowbase,
                        int h, int t, bool clampM) {
    #pragma unroll
    for (int rr = 0; rr < 2; ++rr) {
      int rowblk = h * 128 + (wid * 2 + rr) * 8;       // uniform per wave
      int grow = rowbase + rowblk + l3;
      if (clampM && grow > M - 1) grow = M - 1;
      const u16* src = G + (size_t)grow * 512 + t * 64 + swz16;
      u16* dstb = ldsmat + rowblk * 64;
      __builtin_amdgcn_global_load_lds(
        (const __attribute__((address_space(1))) void*)(uintptr_t)src,
        (__attribute__((address_space(3))) void*)(uintptr_t)dstb, 16, 0, 0);
    }
  };

  auto load_a = [&](int d, int qm) {
    const u16* Ab = &As[d][0];
    #pragma unroll
    for (int i = 0; i < 4; ++i) {
      int ar = wm * 128 + qm * 64 + i * 16 + fm;
      #pragma unroll
      for (int ks = 0; ks < 2; ++ks)
        af[i][ks] = *(const short8*)(Ab + ar * 64 + ((ks * 32 + fq * 8) ^ ((fm & 7) * 8)));
    }
  };
  auto load_b_all = [&](int d) {
    const u16* Bb = &Bs[d][0];
    #pragma unroll
    for (int j = 0; j < 4; ++j) {
      int bc = wn * 64 + j * 16 + fm;
      #pragma unroll
      for (int ks = 0; ks < 2; ++ks)
        bfr[j][ks] = *(const short8*)(Bb + bc * 64 + ((ks * 32 + fq * 8) ^ ((fm & 7) * 8)));
    }
  };
  auto mma_half = [&](int qm) {
    __builtin_amdgcn_s_setprio(1);
    #pragma unroll
    for (int i = 0; i < 4; ++i)
      #pragma unroll
      for (int j = 0; j < 4; ++j)
        #pragma unroll
        for (int ks = 0; ks < 2; ++ks)
          acc[qm * 4 + i][j] = __builtin_amdgcn_mfma_f32_16x16x32_bf16(
              af[i][ks], bfr[j][ks], acc[qm * 4 + i][j], 0, 0, 0);
    __builtin_amdgcn_s_setprio(0);
  };

  // prologue: tile 0 -> buf 0 (8 loads/wave)
  stage_half(As[0], A, tm, 0, 0, true);
  stage_half(As[0], A, tm, 1, 0, true);
  stage_half(Bs[0], Bt, tn, 0, 0, false);
  stage_half(Bs[0], Bt, tn, 1, 0, false);

  #pragma unroll 2
  for (int t = 0; t < NT; ++t) {
    int d = t & 1;
    if (t + 1 < NT) {
      stage_half(As[d ^ 1], A, tm, 0, t + 1, true);
      stage_half(Bs[d ^ 1], Bt, tn, 0, t + 1, false);
      asm volatile("s_waitcnt vmcnt(4)" ::: "memory");
    } else {
      asm volatile("s_waitcnt vmcnt(0)" ::: "memory");
    }
    __builtin_amdgcn_sched_barrier(0);
    __builtin_amdgcn_s_barrier();          // all waves' tile-t loads landed
    __builtin_amdgcn_sched_barrier(0);
    load_a(d, 0);
    load_b_all(d);
    mma_half(0);                           // 32 MFMA
    if (t + 1 < NT) {
      stage_half(As[d ^ 1], A, tm, 1, t + 1, true);
      stage_half(Bs[d ^ 1], Bt, tn, 1, t + 1, false);
    }
    load_a(d, 1);
    mma_half(1);                           // 32 MFMA
    __builtin_amdgcn_sched_barrier(0);
    __builtin_amdgcn_s_barrier();          // all waves done reading buf d
    __builtin_amdgcn_sched_barrier(0);
  }

  // epilogue: q cols (<512) bf16, k/v cols fp8
  #pragma unroll
  for (int i = 0; i < 8; ++i) {
    int rowb = tm + wm * 128 + i * 16 + fq * 4;
    #pragma unroll
    for (int j = 0; j < 4; ++j) {
      int col = tn + wn * 64 + j * 16 + fm;
      float bvv = bias[col];
      #pragma unroll
      for (int r = 0; r < 4; ++r) {
        int gr = rowb + r;
        if (gr < M) {
          float v = acc[i][j][r] + bvv;
          u8* row_p = Cq + (size_t)gr * 2048;
          if (col < 512) *(u16*)(row_p + 2 * col) = f2bf(v);
          else           row_p[512 + col] = f2fp8(v);
        }
      }
    }
  }
}

// ---- 128x128 bf16 MFMA GEMM, double-buffered LDS (N=512 gemms) ----
// 16B-granule XOR swizzle (g ^= row&3) on BOTH sides: inverse-swizzled global
// source for global_load_lds (dest stays linear, rule #21) + swizzled ds_read.
template<int MODE, bool RELU, bool RES>
__global__ __launch_bounds__(256) void gemm_bt(
  const u16* __restrict__ A, const u16* __restrict__ Bt,
  const float* __restrict__ bias, const float* __restrict__ res,
  float* __restrict__ Cf, u16* __restrict__ Cb, int nbx)
{
  constexpr int M = N_NODES, K = 512;
  __shared__ u16 As[2 * 128 * 32];
  __shared__ u16 Bs[2 * 128 * 32];
  int tid = threadIdx.x;
  int wave = tid >> 6, lane = tid & 63;
  int wg = xcd_remap(blockIdx.x, gridDim.x);   // XCD-chunked: col-blocks of a panel share an XCD's L2
  int tn = (wg % nbx) * 128, tm = (wg / nbx) * 128;
  f32x4 acc[4][4] = {};
  int wm = (wave & 1) * 64, wn = (wave >> 1) * 64;
  int fm = lane & 15, fq = lane >> 4;
  int gsw = (fq ^ (fm & 3)) * 8;               // swizzled read granule (u16 offset)

  auto stage = [&](int buf, int k0) {
    #pragma unroll
    for (int rr = 0; rr < 2; ++rr) {
      int c = rr * 256 + tid;
      int row = c >> 2;
      int cb = (((c & 3) ^ (row & 3)) << 3);   // inverse-swizzled source granule
      int gr = tm + row; if (gr > M - 1) gr = M - 1;
      __builtin_amdgcn_global_load_lds(
        (const __attribute__((address_space(1))) void*)(uintptr_t)(A + (size_t)gr * K + (k0 + cb)),
        (__attribute__((address_space(3))) void*)(uintptr_t)(As + buf * 4096 + (size_t)(rr * 256 + wave * 64) * 8),
        16, 0, 0);
      int brow = tn + row;
      __builtin_amdgcn_global_load_lds(
        (const __attribute__((address_space(1))) void*)(uintptr_t)(Bt + (size_t)brow * K + (k0 + cb)),
        (__attribute__((address_space(3))) void*)(uintptr_t)(Bs + buf * 4096 + (size_t)(rr * 256 + wave * 64) * 8),
        16, 0, 0);
    }
  };

  stage(0, 0);
  #pragma unroll 4
  for (int it = 0; it < K / 32; ++it) {
    int cur = it & 1;
    __syncthreads();                 // drains cur-buf loads (vmcnt(0)+lgkm)
    if (it + 1 < K / 32) stage(cur ^ 1, (it + 1) * 32);  // fly during this MFMA stage
    const u16* Ab = As + cur * 4096;
    const u16* Bb = Bs + cur * 4096;
    short8 af[4], bf_[4];
    #pragma unroll
    for (int i = 0; i < 4; ++i) {
      af[i]  = *(const short8*)(Ab + (wm + i * 16 + fm) * 32 + gsw);
      bf_[i] = *(const short8*)(Bb + (wn + i * 16 + fm) * 32 + gsw);
    }
    #pragma unroll
    for (int mi = 0; mi < 4; ++mi)
      #pragma unroll
      for (int ni = 0; ni < 4; ++ni)
        acc[mi][ni] = __builtin_amdgcn_mfma_f32_16x16x32_bf16(af[mi], bf_[ni], acc[mi][ni], 0, 0, 0);
  }

  #pragma unroll
  for (int mi = 0; mi < 4; ++mi) {
    #pragma unroll
    for (int ni = 0; ni < 4; ++ni) {
      int col = tn + wn + ni * 16 + fm;
      float bvv = bias[col];
      int rowb = tm + wm + mi * 16 + fq * 4;
      #pragma unroll
      for (int r = 0; r < 4; ++r) {
        int gr = rowb + r;
        if (gr < M) {
          float v = acc[mi][ni][r] + bvv;
          if (RELU) v = fmaxf(v, 0.f);
          if (RES)  v += res[(size_t)gr * 512 + col];
          if (MODE == 0) Cf[(size_t)gr * 512 + col] = v;
          else           Cb[(size_t)gr * 512 + col] = f2bf(v);
        }
      }
    }
  }
}

// ---- gather-side online-softmax sparse attention; qkv row = [q bf16 1K | k fp8 512 | v fp8 512] ----
__global__ __launch_bounds__(256) void attn_kernel(
  const u8* __restrict__ qkv,
  const int* __restrict__ row_start, const int* __restrict__ csr_dst,
  u16* __restrict__ ab)
{
  int wave = threadIdx.x >> 6, lane = threadIdx.x & 63;
  int n = blockIdx.x * 4 + wave;
  if (n >= N_NODES) return;
  float qf[8];
  {
    short8 q8 = *(const short8*)(qkv + (size_t)n * 2048 + lane * 16);
    #pragma unroll
    for (int j = 0; j < 8; ++j) qf[j] = bf2f((u16)q8[j]);
  }
  float m = -1e30f, l = 0.f;
  float acc[8];
  #pragma unroll
  for (int j = 0; j < 8; ++j) acc[j] = 0.f;
  int e0 = row_start[n], e1 = row_start[n + 1];
  int deg = e1 - e0;
  if (deg > 0) {
    int koff = 1024 + lane * 8, voff = 1536 + lane * 8;
    int d0 = csr_dst[e0];
    int d1 = (deg > 1) ? csr_dst[e0 + 1] : d0;
    uint2 ku0 = *(const uint2*)(qkv + (size_t)d0 * 2048 + koff);
    uint2 vu0 = *(const uint2*)(qkv + (size_t)d0 * 2048 + voff);
    uint2 ku1 = *(const uint2*)(qkv + (size_t)d1 * 2048 + koff);
    uint2 vu1 = *(const uint2*)(qkv + (size_t)d1 * 2048 + voff);
    for (int t = 0; t < deg; t += 2) {
      int p0 = e0 + t + 2, p1 = e0 + t + 3;
      int dn0 = (p0 < e1) ? csr_dst[p0] : d0;
      int dn1 = (p1 < e1) ? csr_dst[p1] : d0;
      uint2 kn0 = *(const uint2*)(qkv + (size_t)dn0 * 2048 + koff);
      uint2 vn0 = *(const uint2*)(qkv + (size_t)dn0 * 2048 + voff);
      uint2 kn1 = *(const uint2*)(qkv + (size_t)dn1 * 2048 + koff);
      uint2 vn1 = *(const uint2*)(qkv + (size_t)dn1 * 2048 + voff);
      float k0f[8], k1f[8];
      fp8x4_to_f32(ku0.x, k0f); fp8x4_to_f32(ku0.y, k0f + 4);
      fp8x4_to_f32(ku1.x, k1f); fp8x4_to_f32(ku1.y, k1f + 4);
      float s0 = 0.f, s1 = 0.f;
      #pragma unroll
      for (int j = 0; j < 8; ++j) { s0 = fmaf(qf[j], k0f[j], s0); s1 = fmaf(qf[j], k1f[j], s1); }
      s0 += __shfl_xor(s0, 1); s1 += __shfl_xor(s1, 1);
      s0 += __shfl_xor(s0, 2); s1 += __shfl_xor(s1, 2);
      s0 += __shfl_xor(s0, 4); s1 += __shfl_xor(s1, 4);
      s0 += __shfl_xor(s0, 8); s1 += __shfl_xor(s1, 8);
      s0 *= 0.088388347648318447f;
      s1 = (t + 1 < deg) ? s1 * 0.088388347648318447f : -1e30f;
      float mx = fmaxf(m, fmaxf(s0, s1));
      float al = __expf(m - mx);
      float pp0 = __expf(s0 - mx);
      float pp1 = __expf(s1 - mx);
      l = l * al + pp0 + pp1;
      float v0f[8], v1f[8];
      fp8x4_to_f32(vu0.x, v0f); fp8x4_to_f32(vu0.y, v0f + 4);
      fp8x4_to_f32(vu1.x, v1f); fp8x4_to_f32(vu1.y, v1f + 4);
      #pragma unroll
      for (int j = 0; j < 8; ++j)
        acc[j] = fmaf(acc[j], al, fmaf(pp0, v0f[j], pp1 * v1f[j]));
      m = mx;
      ku0 = kn0; vu0 = vn0; ku1 = kn1; vu1 = vn1;
    }
  }
  float rl = (l > 0.f) ? 1.f / l : 0.f;
  short8 o8;
  #pragma unroll
  for (int j = 0; j < 8; ++j) o8[j] = (short)f2bf(acc[j] * rl);
  *(short8*)(ab + (size_t)n * 512 + lane * 8) = o8;
}

// ---------------- host ----------------
extern "C" void kernel_launch(void* const* d_in, const int* in_sizes, int n_in,
                              void* d_out, int out_size, void* d_ws, size_t ws_size,
                              hipStream_t stream)
{
  const float* x0    = (const float*)d_in[0];
  const int*   edge  = (const int*)d_in[1];
  const float* noise = (const float*)d_in[2];
  const float* f_w1  = (const float*)d_in[3];
  const float* f_b1  = (const float*)d_in[4];
  const float* f_w2  = (const float*)d_in[5];
  const float* f_b2  = (const float*)d_in[6];
  const float* s1_w  = (const float*)d_in[7];
  const float* s1_b  = (const float*)d_in[8];
  const float* b1_w  = (const float*)d_in[9];
  const float* b1_b  = (const float*)d_in[10];
  const float* wq    = (const float*)d_in[11];
  const float* bq    = (const float*)d_in[12];
  const float* wk    = (const float*)d_in[13];
  const float* bk    = (const float*)d_in[14];
  const float* wv    = (const float*)d_in[15];
  const float* bv    = (const float*)d_in[16];
  const float* wo    = (const float*)d_in[17];
  const float* bo    = (const float*)d_in[18];
  const float* s2_w  = (const float*)d_in[19];
  const float* s2_b  = (const float*)d_in[20];
  const float* b2_w  = (const float*)d_in[21];
  const float* b2_b  = (const float*)d_in[22];
  const float* m_w1  = (const float*)d_in[23];
  const float* m_b1  = (const float*)d_in[24];
  const float* m_w2  = (const float*)d_in[25];
  const float* m_b2  = (const float*)d_in[26];
  float* xout = (float*)d_out;

  char* w = (char*)d_ws;
  auto alloc = [&](size_t bytes) -> char* {
    char* p = w; w += (bytes + 255) & ~(size_t)255; return p;
  };
  u16*  Wt     = (u16*)alloc(24ull * 512 * 512 * 2);
  float* cond  = (float*)alloc((size_t)N_NODES * 16 * 4);
  float* bqkv  = (float*)alloc(4 * 1536 * 4);
  u16*  ybf    = (u16*)alloc((size_t)N_NODES * 512 * 2);
  u16*  hbf    = (u16*)alloc((size_t)N_NODES * 512 * 2);
  u8*   qkvb   = (u8*)alloc((size_t)N_NODES * 2048);
  int*  deg    = (int*)alloc((size_t)N_NODES * 4);
  int*  cursor = (int*)alloc((size_t)N_NODES * 4);
  int*  rowst  = (int*)alloc((size_t)(N_NODES + 1) * 4);
  int*  csrd   = (int*)alloc((size_t)N_EDGES * 4);

  conv_weights<<<dim3(16, 16, 24), dim3(32, 8), 0, stream>>>(wq, wk, wv, wo, m_w1, m_w2, Wt);
  cond_kernel<<<(N_NODES + 255) / 256, 256, 0, stream>>>(noise, f_w1, f_b1, f_w2, f_b2, cond);
  pack_bias<<<(4 * 1536 + 255) / 256, 256, 0, stream>>>(bq, bk, bv, bqkv);
  hipMemsetAsync(deg, 0, (size_t)N_NODES * 4, stream);
  hipMemsetAsync(cursor, 0, (size_t)N_NODES * 4, stream);
  const int* src = edge;
  const int* dst = edge + N_EDGES;
  hist_kernel<<<(N_EDGES + 255) / 256, 256, 0, stream>>>(src, deg);
  scan_kernel<<<1, 1024, 0, stream>>>(deg, rowst);
  scatter_kernel<<<(N_EDGES + 255) / 256, 256, 0, stream>>>(src, dst, rowst, cursor, csrd);

  const int g_ln  = (N_NODES + LN_NPB - 1) / LN_NPB;   // 1281 strip blocks
  const int g_qkv = 6 * ((N_NODES + 255) / 256);       // 966 blocks, 256x256 tiles
  const int g_512 = 4 * ((N_NODES + 127) / 128);       // 1284 blocks, 128x128 tiles
  const float* xin = x0;
  for (int i = 0; i < 4; ++i) {
    const u16* Wb = Wt + (size_t)i * 6 * 262144;
    ln_film<<<g_ln, 256, 0, stream>>>(xin, cond, s1_w + i * 8192, s1_b + i * 512,
                                      b1_w + i * 8192, b1_b + i * 512, ybf);
    gemm256_qkv<<<g_qkv, 512, 0, stream>>>(ybf, Wb, bqkv + i * 1536, qkvb);
    attn_kernel<<<(N_NODES + 3) / 4, 256, 0, stream>>>(qkvb, rowst, csrd, ybf);
    gemm_bt<0, false, true><<<g_512, 256, 0, stream>>>(ybf, Wb + 3 * 262144,
                                                       bo + i * 512, xin, xout, nullptr, 4);
    ln_film<<<g_ln, 256, 0, stream>>>(xout, cond, s2_w + i * 8192, s2_b + i * 512,
                                      b2_w + i * 8192, b2_b + i * 512, ybf);
    gemm_bt<1, true, false><<<g_512, 256, 0, stream>>>(ybf, Wb + 4 * 262144,
                                                       m_b1 + i * 512, nullptr, nullptr, hbf, 4);
    gemm_bt<0, false, true><<<g_512, 256, 0, stream>>>(hbf, Wb + 5 * 262144,
                                                       m_b2 + i * 512, xout, xout, nullptr, 4);
    xin = xout;
  }
}